// Round 1
// baseline (4558.621 us; speedup 1.0000x reference)
//
#include <hip/hip_runtime.h>

#define D 128
#define N_ITER 20

// ---------------- mask dtype detection ----------------
// jax bool may arrive as u8 (1B/elem) or int32 (4B/elem) 0/1 values.
// If int32: every byte at offset i%4!=0 within the first N bytes is 0.
// If u8: ~37.5% of those bytes are 1 (bernoulli 0.5). Deterministic test.
__global__ void k_detect(const unsigned char* __restrict__ m, int nbytes, int* flag) {
    __shared__ int s;
    if (threadIdx.x == 0) s = 0;
    __syncthreads();
    int c = 0;
    for (int i = threadIdx.x; i < nbytes; i += 256)
        if ((i & 3) && m[i]) c++;
    atomicAdd(&s, c);
    __syncthreads();
    if (threadIdx.x == 0) *flag = (s > 0) ? 1 : 0;
}

__global__ void k_mask(const void* __restrict__ mraw, const int* __restrict__ flag,
                       unsigned char* __restrict__ m8, int n) {
    int i = blockIdx.x * 256 + threadIdx.x;
    if (i >= n) return;
    unsigned char v;
    if (*flag) {
        v = ((const unsigned char*)mraw)[i] != 0;
    } else {
        v = ((const int*)mraw)[i] != 0;
    }
    m8[i] = v;
}

// ---------------- degree counting ----------------
__global__ void k_deg(const int* __restrict__ row, const int* __restrict__ col, int E,
                      int* __restrict__ deg, int* __restrict__ rdeg) {
    int e = blockIdx.x * 256 + threadIdx.x;
    if (e >= E) return;
    atomicAdd(&deg[col[e]], 1);   // normalization degree (by col)
    atomicAdd(&rdeg[row[e]], 1);  // CSR row degree (by row)
}

__global__ void k_dis(const int* __restrict__ deg, float* __restrict__ dis, int n) {
    int i = blockIdx.x * 256 + threadIdx.x;
    if (i >= n) return;
    int d = deg[i];
    dis[i] = (d > 0) ? rsqrtf((float)d) : 0.f;
}

// ---------------- exclusive scan of rdeg -> row_off (chunked, CH=2048) ----------------
__global__ void k_scan1(const int* __restrict__ rdeg, int* __restrict__ csum, int n) {
    __shared__ int sh[256];
    int base = blockIdx.x * 2048;
    int t = threadIdx.x;
    int s = 0;
    for (int j = 0; j < 8; j++) {
        int i = base + t * 8 + j;
        if (i < n) s += rdeg[i];
    }
    sh[t] = s;
    __syncthreads();
    for (int o = 128; o > 0; o >>= 1) {
        if (t < o) sh[t] += sh[t + o];
        __syncthreads();
    }
    if (t == 0) csum[blockIdx.x] = sh[0];
}

__global__ void k_scan2(int* __restrict__ csum, int nch, int* __restrict__ row_off, int n, int E) {
    if (threadIdx.x == 0) {
        int acc = 0;
        for (int i = 0; i < nch; i++) { int v = csum[i]; csum[i] = acc; acc += v; }
        row_off[n] = E;
    }
}

__global__ void k_scan3(const int* __restrict__ rdeg, const int* __restrict__ csum,
                        int* __restrict__ row_off, int n) {
    __shared__ int sh[256];
    int base = blockIdx.x * 2048;
    int t = threadIdx.x;
    int loc[8];
    int s = 0;
    for (int j = 0; j < 8; j++) {
        int i = base + t * 8 + j;
        int v = (i < n) ? rdeg[i] : 0;
        loc[j] = s;
        s += v;
    }
    sh[t] = s;
    __syncthreads();
    // Hillis-Steele inclusive scan (double-sync, in place)
    for (int o = 1; o < 256; o <<= 1) {
        int v = (t >= o) ? sh[t - o] : 0;
        __syncthreads();
        sh[t] += v;
        __syncthreads();
    }
    int toff = csum[blockIdx.x] + ((t > 0) ? sh[t - 1] : 0);
    for (int j = 0; j < 8; j++) {
        int i = base + t * 8 + j;
        if (i < n) row_off[i] = toff + loc[j];
    }
}

// ---------------- scatter edges into CSR ----------------
__global__ void k_scatter(const int* __restrict__ row, const int* __restrict__ col, int E,
                          const int* __restrict__ row_off, int* __restrict__ cursor,
                          const float* __restrict__ dis, int* __restrict__ col_s,
                          float* __restrict__ w_s) {
    int e = blockIdx.x * 256 + threadIdx.x;
    if (e >= E) return;
    int r = row[e], c = col[e];
    int p = row_off[r] + atomicAdd(&cursor[r], 1);
    col_s[p] = c;
    w_s[p] = dis[r] * dis[c];
}

// ---------------- init both ping-pong buffers: masked rows = x, others = 0 ----------------
__global__ void k_init(const float* __restrict__ x, const unsigned char* __restrict__ m8,
                       float* __restrict__ A, float* __restrict__ B, int nvec) {
    int i = blockIdx.x * 256 + threadIdx.x;  // float4 index, 32 per node
    if (i >= nvec) return;
    int node = i >> 5;
    float4 v;
    if (m8[node]) v = ((const float4*)x)[i];
    else          v = make_float4(0.f, 0.f, 0.f, 0.f);
    ((float4*)A)[i] = v;
    ((float4*)B)[i] = v;
}

// ---------------- propagation: one wave per (unmasked) row ----------------
__global__ __launch_bounds__(256) void k_prop(const float* __restrict__ src,
                                              float* __restrict__ dst,
                                              const unsigned char* __restrict__ m8,
                                              const int* __restrict__ row_off,
                                              const int* __restrict__ col_s,
                                              const float* __restrict__ w_s, int n) {
    int wid = (blockIdx.x * 256 + threadIdx.x) >> 6;  // one wave per row
    int lane = threadIdx.x & 63;
    if (wid >= n) return;
    if (m8[wid]) return;  // masked rows stay = x (pre-filled in both buffers)
    int beg = row_off[wid], end = row_off[wid + 1];
    float ax = 0.f, ay = 0.f;
    const float* sb = src + lane * 2;
    for (int e = beg; e < end; e++) {
        int c = col_s[e];
        float w = w_s[e];
        float2 v = *(const float2*)(sb + (size_t)c * D);
        ax += w * v.x;
        ay += w * v.y;
    }
    *(float2*)(dst + (size_t)wid * D + lane * 2) = make_float2(ax, ay);
}

extern "C" void kernel_launch(void* const* d_in, const int* in_sizes, int n_in,
                              void* d_out, int out_size, void* d_ws, size_t ws_size,
                              hipStream_t stream) {
    const float* x = (const float*)d_in[0];
    const int* ei = (const int*)d_in[1];
    const void* mraw = d_in[2];

    const int N = in_sizes[0] / D;     // 100000
    const int E = in_sizes[1] / 2;     // 3200000
    const int* row = ei;
    const int* col = ei + E;

    float* A = (float*)d_out;          // ping buffer (holds final result: 20 even)
    char* ws = (char*)d_ws;
    size_t off = 0;
    float* B = (float*)(ws + off);          off += (size_t)N * D * 4;   // pong buffer
    int* col_s = (int*)(ws + off);          off += (size_t)E * 4;       // CSR cols
    float* w_s = (float*)(ws + off);        off += (size_t)E * 4;       // CSR weights
    int* row_off = (int*)(ws + off);        off += (size_t)(N + 1) * 4; // CSR offsets
    int* zblock = (int*)(ws + off);         off += (size_t)3 * N * 4;   // deg|rdeg|cursor
    int* deg = zblock;
    int* rdeg = zblock + N;
    int* cursor = zblock + 2 * N;
    float* dis = (float*)(ws + off);        off += (size_t)N * 4;
    unsigned char* m8 = (unsigned char*)(ws + off); off += (size_t)N;
    off = (off + 255) & ~(size_t)255;
    int* csum = (int*)(ws + off);           off += 256 * 4;
    int* flag = (int*)(ws + off);           off += 4;

    hipMemsetAsync(zblock, 0, (size_t)3 * N * 4, stream);

    k_detect<<<1, 256, 0, stream>>>((const unsigned char*)mraw, N, flag);
    k_mask<<<(N + 255) / 256, 256, 0, stream>>>(mraw, flag, m8, N);
    k_deg<<<(E + 255) / 256, 256, 0, stream>>>(row, col, E, deg, rdeg);
    k_dis<<<(N + 255) / 256, 256, 0, stream>>>(deg, dis, N);

    int nch = (N + 2047) / 2048;
    k_scan1<<<nch, 256, 0, stream>>>(rdeg, csum, N);
    k_scan2<<<1, 64, 0, stream>>>(csum, nch, row_off, N, E);
    k_scan3<<<nch, 256, 0, stream>>>(rdeg, csum, row_off, N);

    k_scatter<<<(E + 255) / 256, 256, 0, stream>>>(row, col, E, row_off, cursor, dis, col_s, w_s);

    int nvec = N * (D / 4);
    k_init<<<(nvec + 255) / 256, 256, 0, stream>>>(x, m8, A, B, nvec);

    // ping-pong: out0 in A; iter1 A->B, iter2 B->A, ... iter20 ends in A (=d_out)
    float* src = A;
    float* dst = B;
    int waves = N;
    int blocks = (waves + 3) / 4;  // 4 waves per 256-thread block
    for (int it = 0; it < N_ITER; it++) {
        k_prop<<<blocks, 256, 0, stream>>>(src, dst, m8, row_off, col_s, w_s, N);
        float* t = src; src = dst; dst = t;
    }
}

// Round 2
// 3008.923 us; speedup vs baseline: 1.5150x; 1.5150x over previous
//
#include <hip/hip_runtime.h>

#define D 128
#define N_ITER 20

// ---------------- mask dtype detection ----------------
__global__ void k_detect(const unsigned char* __restrict__ m, int nbytes, int* flag) {
    __shared__ int s;
    if (threadIdx.x == 0) s = 0;
    __syncthreads();
    int c = 0;
    for (int i = threadIdx.x; i < nbytes; i += 256)
        if ((i & 3) && m[i]) c++;
    atomicAdd(&s, c);
    __syncthreads();
    if (threadIdx.x == 0) *flag = (s > 0) ? 1 : 0;
}

__global__ void k_mask(const void* __restrict__ mraw, const int* __restrict__ flag,
                       unsigned char* __restrict__ m8, int n) {
    int i = blockIdx.x * 256 + threadIdx.x;
    if (i >= n) return;
    unsigned char v;
    if (*flag) {
        v = ((const unsigned char*)mraw)[i] != 0;
    } else {
        v = ((const int*)mraw)[i] != 0;
    }
    m8[i] = v;
}

// ---------------- degree counting ----------------
__global__ void k_deg(const int* __restrict__ row, const int* __restrict__ col, int E,
                      int* __restrict__ deg, int* __restrict__ rdeg) {
    int e = blockIdx.x * 256 + threadIdx.x;
    if (e >= E) return;
    atomicAdd(&deg[col[e]], 1);   // normalization degree (by col)
    atomicAdd(&rdeg[row[e]], 1);  // CSR row degree (by row)
}

__global__ void k_dis(const int* __restrict__ deg, float* __restrict__ dis, int n) {
    int i = blockIdx.x * 256 + threadIdx.x;
    if (i >= n) return;
    int d = deg[i];
    dis[i] = (d > 0) ? rsqrtf((float)d) : 0.f;
}

// ---------------- exclusive scan of rdeg -> row_off (chunked, CH=2048) ----------------
__global__ void k_scan1(const int* __restrict__ rdeg, int* __restrict__ csum, int n) {
    __shared__ int sh[256];
    int base = blockIdx.x * 2048;
    int t = threadIdx.x;
    int s = 0;
    for (int j = 0; j < 8; j++) {
        int i = base + t * 8 + j;
        if (i < n) s += rdeg[i];
    }
    sh[t] = s;
    __syncthreads();
    for (int o = 128; o > 0; o >>= 1) {
        if (t < o) sh[t] += sh[t + o];
        __syncthreads();
    }
    if (t == 0) csum[blockIdx.x] = sh[0];
}

__global__ void k_scan2(int* __restrict__ csum, int nch, int* __restrict__ row_off, int n, int E) {
    if (threadIdx.x == 0) {
        int acc = 0;
        for (int i = 0; i < nch; i++) { int v = csum[i]; csum[i] = acc; acc += v; }
        row_off[n] = E;
    }
}

__global__ void k_scan3(const int* __restrict__ rdeg, const int* __restrict__ csum,
                        int* __restrict__ row_off, int n) {
    __shared__ int sh[256];
    int base = blockIdx.x * 2048;
    int t = threadIdx.x;
    int loc[8];
    int s = 0;
    for (int j = 0; j < 8; j++) {
        int i = base + t * 8 + j;
        int v = (i < n) ? rdeg[i] : 0;
        loc[j] = s;
        s += v;
    }
    sh[t] = s;
    __syncthreads();
    for (int o = 1; o < 256; o <<= 1) {
        int v = (t >= o) ? sh[t - o] : 0;
        __syncthreads();
        sh[t] += v;
        __syncthreads();
    }
    int toff = csum[blockIdx.x] + ((t > 0) ? sh[t - 1] : 0);
    for (int j = 0; j < 8; j++) {
        int i = base + t * 8 + j;
        if (i < n) row_off[i] = toff + loc[j];
    }
}

// ---------------- scatter edges into CSR ----------------
__global__ void k_scatter(const int* __restrict__ row, const int* __restrict__ col, int E,
                          const int* __restrict__ row_off, int* __restrict__ cursor,
                          const float* __restrict__ dis, int* __restrict__ col_s,
                          float* __restrict__ w_s) {
    int e = blockIdx.x * 256 + threadIdx.x;
    if (e >= E) return;
    int r = row[e], c = col[e];
    int p = row_off[r] + atomicAdd(&cursor[r], 1);
    col_s[p] = c;
    w_s[p] = dis[r] * dis[c];
}

// ---------------- compact unmasked rows ----------------
__global__ void k_compact(const unsigned char* __restrict__ m8, int n,
                          int* __restrict__ rows_c, int* __restrict__ cnt) {
    int i = blockIdx.x * 256 + threadIdx.x;
    if (i >= n) return;
    if (!m8[i]) {
        int p = atomicAdd(cnt, 1);
        rows_c[p] = i;
    }
}

// ---------------- init both ping-pong buffers: masked rows = x, others = 0 ----------------
__global__ void k_init(const float* __restrict__ x, const unsigned char* __restrict__ m8,
                       float* __restrict__ A, float* __restrict__ B, int nvec) {
    int i = blockIdx.x * 256 + threadIdx.x;  // float4 index, 32 per node
    if (i >= nvec) return;
    int node = i >> 5;
    float4 v;
    if (m8[node]) v = ((const float4*)x)[i];
    else          v = make_float4(0.f, 0.f, 0.f, 0.f);
    ((float4*)A)[i] = v;
    ((float4*)B)[i] = v;
}

// ---------------- propagation: one wave per unmasked row, 4-way edge unroll ----------------
__global__ __launch_bounds__(256) void k_prop(const float* __restrict__ src,
                                              float* __restrict__ dst,
                                              const int* __restrict__ rows_c,
                                              const int* __restrict__ cnt_p,
                                              const int* __restrict__ row_off,
                                              const int* __restrict__ col_s,
                                              const float* __restrict__ w_s) {
    int wid = (blockIdx.x * 256 + threadIdx.x) >> 6;  // one wave per compacted row
    int lane = threadIdx.x & 63;
    int cnt = *cnt_p;
    if (wid >= cnt) return;
    int r = rows_c[wid];
    int beg = row_off[r], end = row_off[r + 1];

    float ax0 = 0.f, ay0 = 0.f, ax1 = 0.f, ay1 = 0.f;
    float ax2 = 0.f, ay2 = 0.f, ax3 = 0.f, ay3 = 0.f;
    const float* sb = src + lane * 2;

    int e = beg;
    for (; e + 4 <= end; e += 4) {
        int c0 = col_s[e], c1 = col_s[e + 1], c2 = col_s[e + 2], c3 = col_s[e + 3];
        float w0 = w_s[e], w1 = w_s[e + 1], w2 = w_s[e + 2], w3 = w_s[e + 3];
        float2 v0 = *(const float2*)(sb + (size_t)c0 * D);
        float2 v1 = *(const float2*)(sb + (size_t)c1 * D);
        float2 v2 = *(const float2*)(sb + (size_t)c2 * D);
        float2 v3 = *(const float2*)(sb + (size_t)c3 * D);
        ax0 += w0 * v0.x; ay0 += w0 * v0.y;
        ax1 += w1 * v1.x; ay1 += w1 * v1.y;
        ax2 += w2 * v2.x; ay2 += w2 * v2.y;
        ax3 += w3 * v3.x; ay3 += w3 * v3.y;
    }
    for (; e < end; e++) {
        int c = col_s[e];
        float w = w_s[e];
        float2 v = *(const float2*)(sb + (size_t)c * D);
        ax0 += w * v.x; ay0 += w * v.y;
    }
    float ax = (ax0 + ax1) + (ax2 + ax3);
    float ay = (ay0 + ay1) + (ay2 + ay3);
    *(float2*)(dst + (size_t)r * D + lane * 2) = make_float2(ax, ay);
}

extern "C" void kernel_launch(void* const* d_in, const int* in_sizes, int n_in,
                              void* d_out, int out_size, void* d_ws, size_t ws_size,
                              hipStream_t stream) {
    const float* x = (const float*)d_in[0];
    const int* ei = (const int*)d_in[1];
    const void* mraw = d_in[2];

    const int N = in_sizes[0] / D;     // 100000
    const int E = in_sizes[1] / 2;     // 3200000
    const int* row = ei;
    const int* col = ei + E;

    float* A = (float*)d_out;          // ping buffer (holds final result: 20 even)
    char* ws = (char*)d_ws;
    size_t off = 0;
    float* B = (float*)(ws + off);          off += (size_t)N * D * 4;   // pong buffer
    int* col_s = (int*)(ws + off);          off += (size_t)E * 4;       // CSR cols
    float* w_s = (float*)(ws + off);        off += (size_t)E * 4;       // CSR weights
    int* row_off = (int*)(ws + off);        off += (size_t)(N + 1) * 4; // CSR offsets
    int* zblock = (int*)(ws + off);         off += (size_t)(3 * N + 1) * 4; // deg|rdeg|cursor|cnt
    int* deg = zblock;
    int* rdeg = zblock + N;
    int* cursor = zblock + 2 * N;
    int* cnt = zblock + 3 * N;
    float* dis = (float*)(ws + off);        off += (size_t)N * 4;
    int* rows_c = (int*)(ws + off);         off += (size_t)N * 4;
    unsigned char* m8 = (unsigned char*)(ws + off); off += (size_t)N;
    off = (off + 255) & ~(size_t)255;
    int* csum = (int*)(ws + off);           off += 256 * 4;
    int* flag = (int*)(ws + off);           off += 4;

    hipMemsetAsync(zblock, 0, (size_t)(3 * N + 1) * 4, stream);

    k_detect<<<1, 256, 0, stream>>>((const unsigned char*)mraw, N, flag);
    k_mask<<<(N + 255) / 256, 256, 0, stream>>>(mraw, flag, m8, N);
    k_deg<<<(E + 255) / 256, 256, 0, stream>>>(row, col, E, deg, rdeg);
    k_dis<<<(N + 255) / 256, 256, 0, stream>>>(deg, dis, N);

    int nch = (N + 2047) / 2048;
    k_scan1<<<nch, 256, 0, stream>>>(rdeg, csum, N);
    k_scan2<<<1, 64, 0, stream>>>(csum, nch, row_off, N, E);
    k_scan3<<<nch, 256, 0, stream>>>(rdeg, csum, row_off, N);

    k_scatter<<<(E + 255) / 256, 256, 0, stream>>>(row, col, E, row_off, cursor, dis, col_s, w_s);
    k_compact<<<(N + 255) / 256, 256, 0, stream>>>(m8, N, rows_c, cnt);

    int nvec = N * (D / 4);
    k_init<<<(nvec + 255) / 256, 256, 0, stream>>>(x, m8, A, B, nvec);

    // ping-pong: out0 in A; iter1 A->B, ... iter20 ends in A (=d_out)
    float* src = A;
    float* dst = B;
    int blocks = (N + 3) / 4;  // 4 waves per 256-thread block, upper bound on cnt
    for (int it = 0; it < N_ITER; it++) {
        k_prop<<<blocks, 256, 0, stream>>>(src, dst, rows_c, cnt, row_off, col_s, w_s);
        float* t = src; src = dst; dst = t;
    }
}

// Round 3
// 1636.554 us; speedup vs baseline: 2.7855x; 1.8386x over previous
//
#include <hip/hip_runtime.h>
#include <hip/hip_fp16.h>

#define D 128
#define N_ITER 20

// ---------------- mask dtype detection ----------------
__global__ void k_detect(const unsigned char* __restrict__ m, int nbytes, int* flag) {
    __shared__ int s;
    if (threadIdx.x == 0) s = 0;
    __syncthreads();
    int c = 0;
    for (int i = threadIdx.x; i < nbytes; i += 256)
        if ((i & 3) && m[i]) c++;
    atomicAdd(&s, c);
    __syncthreads();
    if (threadIdx.x == 0) *flag = (s > 0) ? 1 : 0;
}

__global__ void k_mask(const void* __restrict__ mraw, const int* __restrict__ flag,
                       unsigned char* __restrict__ m8, int n) {
    int i = blockIdx.x * 256 + threadIdx.x;
    if (i >= n) return;
    unsigned char v;
    if (*flag) {
        v = ((const unsigned char*)mraw)[i] != 0;
    } else {
        v = ((const int*)mraw)[i] != 0;
    }
    m8[i] = v;
}

// ---------------- degree counting ----------------
// deg[col] over ALL edges (normalization); rdeg[row] only for unmasked rows
// (masked rows' CSR segments are never read).
__global__ void k_deg(const int* __restrict__ row, const int* __restrict__ col, int E,
                      const unsigned char* __restrict__ m8,
                      int* __restrict__ deg, int* __restrict__ rdeg) {
    int e = blockIdx.x * 256 + threadIdx.x;
    if (e >= E) return;
    atomicAdd(&deg[col[e]], 1);
    int r = row[e];
    if (!m8[r]) atomicAdd(&rdeg[r], 1);
}

__global__ void k_dis(const int* __restrict__ deg, float* __restrict__ dis, int n) {
    int i = blockIdx.x * 256 + threadIdx.x;
    if (i >= n) return;
    int d = deg[i];
    dis[i] = (d > 0) ? rsqrtf((float)d) : 0.f;
}

// ---------------- exclusive scan of rdeg -> row_off ----------------
__global__ void k_scan1(const int* __restrict__ rdeg, int* __restrict__ csum, int n) {
    __shared__ int sh[256];
    int base = blockIdx.x * 2048;
    int t = threadIdx.x;
    int s = 0;
    for (int j = 0; j < 8; j++) {
        int i = base + t * 8 + j;
        if (i < n) s += rdeg[i];
    }
    sh[t] = s;
    __syncthreads();
    for (int o = 128; o > 0; o >>= 1) {
        if (t < o) sh[t] += sh[t + o];
        __syncthreads();
    }
    if (t == 0) csum[blockIdx.x] = sh[0];
}

__global__ void k_scan2(int* __restrict__ csum, int nch, int* __restrict__ row_off, int n) {
    if (threadIdx.x == 0) {
        int acc = 0;
        for (int i = 0; i < nch; i++) { int v = csum[i]; csum[i] = acc; acc += v; }
        row_off[n] = acc;   // total filtered edge count
    }
}

__global__ void k_scan3(const int* __restrict__ rdeg, const int* __restrict__ csum,
                        int* __restrict__ row_off, int n) {
    __shared__ int sh[256];
    int base = blockIdx.x * 2048;
    int t = threadIdx.x;
    int loc[8];
    int s = 0;
    for (int j = 0; j < 8; j++) {
        int i = base + t * 8 + j;
        int v = (i < n) ? rdeg[i] : 0;
        loc[j] = s;
        s += v;
    }
    sh[t] = s;
    __syncthreads();
    for (int o = 1; o < 256; o <<= 1) {
        int v = (t >= o) ? sh[t - o] : 0;
        __syncthreads();
        sh[t] += v;
        __syncthreads();
    }
    int toff = csum[blockIdx.x] + ((t > 0) ? sh[t - 1] : 0);
    for (int j = 0; j < 8; j++) {
        int i = base + t * 8 + j;
        if (i < n) row_off[i] = toff + loc[j];
    }
}

// ---------------- scatter (filtered) edges into CSR: col only ----------------
__global__ void k_scatter(const int* __restrict__ row, const int* __restrict__ col, int E,
                          const unsigned char* __restrict__ m8,
                          const int* __restrict__ row_off, int* __restrict__ cursor,
                          int* __restrict__ col_s) {
    int e = blockIdx.x * 256 + threadIdx.x;
    if (e >= E) return;
    int r = row[e];
    if (m8[r]) return;
    int p = row_off[r] + atomicAdd(&cursor[r], 1);
    col_s[p] = col[e];
}

// ---------------- compact unmasked rows ----------------
__global__ void k_compact(const unsigned char* __restrict__ m8, int n,
                          int* __restrict__ rows_c, int* __restrict__ cnt) {
    int i = blockIdx.x * 256 + threadIdx.x;
    if (i >= n) return;
    if (!m8[i]) {
        int p = atomicAdd(cnt, 1);
        rows_c[p] = i;
    }
}

// ---------------- init: u0 = mask ? dis*x : 0 (half, both buffers); d_out masked = x ----------------
__global__ void k_init(const float* __restrict__ x, const unsigned char* __restrict__ m8,
                       const float* __restrict__ dis,
                       __half2* __restrict__ uA, __half2* __restrict__ uB,
                       float* __restrict__ out, int nvec) {
    int i = blockIdx.x * 256 + threadIdx.x;  // float4 index, 32 per node
    if (i >= nvec) return;
    int node = i >> 5;
    __half2 h0, h1;
    if (m8[node]) {
        float4 v = ((const float4*)x)[i];
        ((float4*)out)[i] = v;               // masked rows of d_out = x exactly
        float d = dis[node];
        h0 = __floats2half2_rn(d * v.x, d * v.y);
        h1 = __floats2half2_rn(d * v.z, d * v.w);
    } else {
        h0 = __floats2half2_rn(0.f, 0.f);
        h1 = h0;
    }
    uA[i * 2] = h0; uA[i * 2 + 1] = h1;
    uB[i * 2] = h0; uB[i * 2 + 1] = h1;
}

// ---------------- propagation: one wave per unmasked row, 8-way unroll ----------------
// u_new[r] = dis[r]^2 * sum_e u[col_e]   (intermediate, half output)
// out[r]   = dis[r]   * sum_e u[col_e]   (final, fp32 output)
template <bool FINAL>
__global__ __launch_bounds__(256) void k_prop(const __half2* __restrict__ src,
                                              void* __restrict__ dst,
                                              const int* __restrict__ rows_c,
                                              const int* __restrict__ cnt_p,
                                              const int* __restrict__ row_off,
                                              const int* __restrict__ col_s,
                                              const float* __restrict__ dis) {
    int wid = __builtin_amdgcn_readfirstlane(blockIdx.x * 4 + (threadIdx.x >> 6));
    int lane = threadIdx.x & 63;
    if (wid >= *cnt_p) return;
    int r = __builtin_amdgcn_readfirstlane(rows_c[wid]);
    int beg = __builtin_amdgcn_readfirstlane(row_off[r]);
    int end = __builtin_amdgcn_readfirstlane(row_off[r + 1]);

    const __half2* sb = src + lane;   // lane-th half2 of each row (row stride 64 half2)

    float ax0 = 0.f, ay0 = 0.f, ax1 = 0.f, ay1 = 0.f;
    float ax2 = 0.f, ay2 = 0.f, ax3 = 0.f, ay3 = 0.f;

    int e = beg;
    for (; e + 8 <= end; e += 8) {
        int c[8];
#pragma unroll
        for (int j = 0; j < 8; j++) c[j] = col_s[e + j];
        __half2 h[8];
#pragma unroll
        for (int j = 0; j < 8; j++) h[j] = sb[(size_t)c[j] * 64];
#pragma unroll
        for (int j = 0; j < 8; j++) {
            float2 v = __half22float2(h[j]);
            switch (j & 3) {
                case 0: ax0 += v.x; ay0 += v.y; break;
                case 1: ax1 += v.x; ay1 += v.y; break;
                case 2: ax2 += v.x; ay2 += v.y; break;
                default: ax3 += v.x; ay3 += v.y; break;
            }
        }
    }
    for (; e < end; e++) {
        int c = col_s[e];
        float2 v = __half22float2(sb[(size_t)c * 64]);
        ax0 += v.x; ay0 += v.y;
    }
    float ax = (ax0 + ax1) + (ax2 + ax3);
    float ay = (ay0 + ay1) + (ay2 + ay3);

    float d = dis[r];
    if (FINAL) {
        float s = d;
        ((float2*)dst)[(size_t)r * 64 + lane] = make_float2(s * ax, s * ay);
    } else {
        float s = d * d;
        ((__half2*)dst)[(size_t)r * 64 + lane] = __floats2half2_rn(s * ax, s * ay);
    }
}

extern "C" void kernel_launch(void* const* d_in, const int* in_sizes, int n_in,
                              void* d_out, int out_size, void* d_ws, size_t ws_size,
                              hipStream_t stream) {
    const float* x = (const float*)d_in[0];
    const int* ei = (const int*)d_in[1];
    const void* mraw = d_in[2];

    const int N = in_sizes[0] / D;     // 100000
    const int E = in_sizes[1] / 2;     // 3200000
    const int* row = ei;
    const int* col = ei + E;

    char* ws = (char*)d_ws;
    size_t off = 0;
    __half2* uA = (__half2*)(ws + off);     off += (size_t)N * D * 2;   // half features
    __half2* uB = (__half2*)(ws + off);     off += (size_t)N * D * 2;
    int* col_s = (int*)(ws + off);          off += (size_t)E * 4;       // CSR cols (filtered)
    int* row_off = (int*)(ws + off);        off += (size_t)(N + 1) * 4;
    int* zblock = (int*)(ws + off);         off += (size_t)(3 * N + 1) * 4; // deg|rdeg|cursor|cnt
    int* deg = zblock;
    int* rdeg = zblock + N;
    int* cursor = zblock + 2 * N;
    int* cnt = zblock + 3 * N;
    float* dis = (float*)(ws + off);        off += (size_t)N * 4;
    int* rows_c = (int*)(ws + off);         off += (size_t)N * 4;
    unsigned char* m8 = (unsigned char*)(ws + off); off += (size_t)N;
    off = (off + 255) & ~(size_t)255;
    int* csum = (int*)(ws + off);           off += 256 * 4;
    int* flag = (int*)(ws + off);           off += 4;

    hipMemsetAsync(zblock, 0, (size_t)(3 * N + 1) * 4, stream);

    k_detect<<<1, 256, 0, stream>>>((const unsigned char*)mraw, N, flag);
    k_mask<<<(N + 255) / 256, 256, 0, stream>>>(mraw, flag, m8, N);
    k_deg<<<(E + 255) / 256, 256, 0, stream>>>(row, col, E, m8, deg, rdeg);
    k_dis<<<(N + 255) / 256, 256, 0, stream>>>(deg, dis, N);

    int nch = (N + 2047) / 2048;
    k_scan1<<<nch, 256, 0, stream>>>(rdeg, csum, N);
    k_scan2<<<1, 64, 0, stream>>>(csum, nch, row_off, N);
    k_scan3<<<nch, 256, 0, stream>>>(rdeg, csum, row_off, N);

    k_scatter<<<(E + 255) / 256, 256, 0, stream>>>(row, col, E, m8, row_off, cursor, col_s);
    k_compact<<<(N + 255) / 256, 256, 0, stream>>>(m8, N, rows_c, cnt);

    int nvec = N * (D / 4);
    k_init<<<(nvec + 255) / 256, 256, 0, stream>>>(x, m8, dis, uA, uB, (float*)d_out, nvec);

    // 19 half-precision iterations ping-pong, then final fp32 iteration into d_out
    __half2* src = uA;
    __half2* dst = uB;
    int blocks = (N + 3) / 4;  // 4 waves per block (upper bound on cnt)
    for (int it = 0; it < N_ITER - 1; it++) {
        k_prop<false><<<blocks, 256, 0, stream>>>(src, dst, rows_c, cnt, row_off, col_s, dis);
        __half2* t = src; src = dst; dst = t;
    }
    k_prop<true><<<blocks, 256, 0, stream>>>(src, d_out, rows_c, cnt, row_off, col_s, dis);
}